// Round 6
// baseline (274.790 us; speedup 1.0000x reference)
//
#include <hip/hip_runtime.h>
#include <hip/hip_bf16.h>
#include <math.h>

#define B 32
#define S 4096
#define H 16
#define QC 1536
#define LORA 512
#define ROPE 64
#define NOPE 128
#define VH 128
#define DM 2048
#define NC 32          // chunks per batch for flash split-K
#define CHUNK (S / NC) // 128 rows per chunk
#define TR 8           // rows per staged LDS tile
#define NT (CHUNK / TR)
#define NKS 24         // k-slices for proj1 split-K (1536/64)

__device__ __constant__ float SCALE_C = 0.07216878364870323f; // 1/sqrt(192)

// ---------------- Kernel 1a: proj partials. grid (NKS=24, 12 col-slices), 256 thr.
__global__ __launch_bounds__(256) void k_proj_part(
    const float* __restrict__ q_c, const float* __restrict__ W_UQ,
    const float* __restrict__ W_QR, float* __restrict__ part) {
    const int ks = blockIdx.x, cs = blockIdx.y, t = threadIdx.x;
    const int k0 = ks * 64;
    __shared__ float qs[64][32]; // [k][b]
    for (int i = t; i < 64 * 32; i += 256) {
        const int k = i >> 5, b2 = i & 31;
        qs[k][b2] = q_c[(size_t)b2 * QC + k0 + k];
    }
    __syncthreads();
    const int tc = t & 63, tb = t >> 6;
    const int col = cs * 256 + tc * 4;
    const float* W; int N, coll;
    if (cs < 8) { W = W_UQ; N = 2048; coll = col; }
    else        { W = W_QR; N = 1024; coll = col - 2048; }
    float4 acc[8];
#pragma unroll
    for (int i = 0; i < 8; i++) acc[i] = make_float4(0.f, 0.f, 0.f, 0.f);
#pragma unroll 4
    for (int k = 0; k < 64; ++k) {
        const float4 w4 = *(const float4*)(W + (size_t)(k0 + k) * N + coll);
        const float4 a1 = *(const float4*)&qs[k][tb * 8];
        const float4 a2 = *(const float4*)&qs[k][tb * 8 + 4];
        acc[0].x += a1.x * w4.x; acc[0].y += a1.x * w4.y; acc[0].z += a1.x * w4.z; acc[0].w += a1.x * w4.w;
        acc[1].x += a1.y * w4.x; acc[1].y += a1.y * w4.y; acc[1].z += a1.y * w4.z; acc[1].w += a1.y * w4.w;
        acc[2].x += a1.z * w4.x; acc[2].y += a1.z * w4.y; acc[2].z += a1.z * w4.z; acc[2].w += a1.z * w4.w;
        acc[3].x += a1.w * w4.x; acc[3].y += a1.w * w4.y; acc[3].z += a1.w * w4.z; acc[3].w += a1.w * w4.w;
        acc[4].x += a2.x * w4.x; acc[4].y += a2.x * w4.y; acc[4].z += a2.x * w4.z; acc[4].w += a2.x * w4.w;
        acc[5].x += a2.y * w4.x; acc[5].y += a2.y * w4.y; acc[5].z += a2.y * w4.z; acc[5].w += a2.y * w4.w;
        acc[6].x += a2.z * w4.x; acc[6].y += a2.z * w4.y; acc[6].z += a2.z * w4.z; acc[6].w += a2.z * w4.w;
        acc[7].x += a2.w * w4.x; acc[7].y += a2.w * w4.y; acc[7].z += a2.w * w4.z; acc[7].w += a2.w * w4.w;
    }
#pragma unroll
    for (int j = 0; j < 8; j++) {
        const int b2 = tb * 8 + j;
        *(float4*)(part + ((size_t)ks * 32 + b2) * 3072 + col) = acc[j];
    }
}

// ---------------- Kernel 1b: reduce 24 partials -> q_t (32x2048), qr (32x1024)
__global__ void k_proj_reduce(const float* __restrict__ part, float* __restrict__ q_t,
                              float* __restrict__ qr) {
    const int idx = blockIdx.x * 256 + threadIdx.x;
    const int b = idx / 768, c4 = idx % 768;
    const int col = c4 * 4;
    float4 acc = make_float4(0.f, 0.f, 0.f, 0.f);
    for (int ks = 0; ks < NKS; ks++) {
        const float4 p = *(const float4*)(part + ((size_t)ks * 32 + b) * 3072 + col);
        acc.x += p.x; acc.y += p.y; acc.z += p.z; acc.w += p.w;
    }
    if (col < 2048) *(float4*)(q_t + (size_t)b * 2048 + col) = acc;
    else            *(float4*)(qr + (size_t)b * 1024 + col - 2048) = acc;
}

// ---------------- Kernel 2: RoPE  (q_pe from qr; kpe_rot from k_pe)
__global__ void k_rope(const float* __restrict__ qr, const float* __restrict__ k_pe,
                       const int* __restrict__ pos_arr, float* __restrict__ q_pe,
                       float* __restrict__ kpe_rot) {
    const int b = blockIdx.x, t = threadIdx.x;
    const int pos = pos_arr[b];
    for (int p = t; p < (H + 1) * 32; p += 256) {
        const int j = p & 31;
        const int grp = p >> 5;
        const double inv = pow(10000.0, -(double)j / 32.0);
        const double f = (double)pos * inv;
        const float c = (float)cos(f), s = (float)sin(f);
        if (grp < H) {
            const float* x = qr + (size_t)b * 1024 + grp * 64;
            float* o = q_pe + (size_t)b * 1024 + grp * 64;
            const float x1 = x[j], x2 = x[j + 32];
            o[j] = x1 * c - x2 * s;
            o[j + 32] = x2 * c + x1 * s;
        } else {
            const float* x = k_pe + (size_t)b * 64;
            float* o = kpe_rot + (size_t)b * 64;
            const float x1 = x[j], x2 = x[j + 32];
            o[j] = x1 * c - x2 * s;
            o[j + 32] = x2 * c + x1 * s;
        }
    }
}

// ---------------- Kernel 3: q_nope[b,h,l] = sum_n q_t[b,h,n] * W_UK[l,h,n]
__global__ __launch_bounds__(256) void k_qnope(
    const float* __restrict__ q_t, const float* __restrict__ W_UK,
    float* __restrict__ q_nope) {
    const int l0 = blockIdx.x * 64, b0 = blockIdx.y * 4, h = blockIdx.z;
    const int t = threadIdx.x;
    __shared__ float qs[4][NOPE];
    for (int i = t; i < 4 * NOPE; i += 256) {
        const int b2 = i >> 7, n = i & 127;
        qs[b2][n] = q_t[(size_t)(b0 + b2) * 2048 + h * NOPE + n];
    }
    __syncthreads();
    const int wave = t >> 6, lane = t & 63;
    const int half = lane >> 5, nl = (lane & 31) * 4;
    for (int sw = 0; sw < 8; ++sw) {
        const int l = l0 + sw * 8 + wave * 2 + half;
        const float4 w4 = *(const float4*)(W_UK + ((size_t)l * H + h) * NOPE + nl);
#pragma unroll
        for (int b2 = 0; b2 < 4; ++b2) {
            const float4 a4 = *(const float4*)&qs[b2][nl];
            float d = a4.x * w4.x + a4.y * w4.y + a4.z * w4.z + a4.w * w4.w;
            d += __shfl_xor(d, 16);
            d += __shfl_xor(d, 8);
            d += __shfl_xor(d, 4);
            d += __shfl_xor(d, 2);
            d += __shfl_xor(d, 1);
            if ((lane & 31) == 0)
                q_nope[((size_t)(b0 + b2) * H + h) * LORA + l] = d;
        }
    }
}

// ---------------- Kernel 4: flash decode, LDS double-buffered via global_load_lds
// NEW mapping: wave w owns heads 4w..4w+3; its 64 lanes chunk the 576-dim row.
// Lane l holds LORA floats [4l,4l+4) and [256+4l, 256+4l+4) plus PE float l.
// Per row per wave: 2 ds_read_b128 + 1 ds_read_b32 (4x less LDS traffic than
// the 16-lane-group layout). Score reduce: 6-level shfl_xor butterfly x4 heads.
__global__ __launch_bounds__(256) void k_flash(
    const float* __restrict__ q_nope, const float* __restrict__ q_pe,
    const float* __restrict__ kv_cache, const float* __restrict__ kpe_cache,
    const float* __restrict__ k_c_normed, const float* __restrict__ kpe_rot,
    const int* __restrict__ pos_arr, float* __restrict__ part_o,
    float* __restrict__ part_ml) {
    __shared__ float lds_kv[2][TR][LORA]; // 32 KB
    __shared__ float lds_pe[2][TR][ROPE]; //  4 KB
    const int blk = blockIdx.x;
    const int b = blk / NC, c = blk % NC;
    const int t = threadIdx.x;
    const int wave = t >> 6, lane = t & 63;
    const int l4 = lane * 4;
    const int pos = pos_arr[b];
    const int s0 = c * CHUNK;
    const int rel = pos - s0;
    const int ptile = (rel >= 0 && rel < CHUNK) ? (rel / TR) : -1;

    const char* kvg = (const char*)kv_cache + (size_t)b * S * LORA * 4;
    const char* peg = (const char*)kpe_cache + (size_t)b * S * ROPE * 4;
    const float* kc_b = k_c_normed + (size_t)b * LORA;
    const float* kr_b = kpe_rot + (size_t)b * ROPE;

    const int wo = wave * 1024 + lane * 16;

    auto stage = [&](int bi, int tile) {
        const char* gk = kvg + (size_t)(s0 + tile * TR) * (LORA * 4);
        char* lk = (char*)&lds_kv[bi][0][0];
#pragma unroll
        for (int i = 0; i < 4; ++i) {
            __builtin_amdgcn_global_load_lds(
                (const __attribute__((address_space(1))) void*)(gk + i * 4096 + wo),
                (__attribute__((address_space(3))) void*)(lk + i * 4096 + wave * 1024),
                16, 0, 0);
        }
        if (t < 128) {
            const char* gp = peg + (size_t)(s0 + tile * TR) * (ROPE * 4);
            char* lp = (char*)&lds_pe[bi][0][0];
            __builtin_amdgcn_global_load_lds(
                (const __attribute__((address_space(1))) void*)(gp + wo),
                (__attribute__((address_space(3))) void*)(lp + wave * 1024),
                16, 0, 0);
        }
    };
    auto patch = [&](int bi, int prow) {
        if (t < 128)
            ((float4*)&lds_kv[bi][prow][0])[t] = ((const float4*)kc_b)[t];
        else if (t < 144)
            ((float4*)&lds_pe[bi][prow][0])[t - 128] = ((const float4*)kr_b)[t - 128];
    };

    // q fragments for this wave's 4 heads, this lane's chunk
    float4 q0[4], q1[4];
    float qp[4];
#pragma unroll
    for (int h = 0; h < 4; ++h) {
        const float* qn = q_nope + ((size_t)b * H + wave * 4 + h) * LORA;
        q0[h] = *(const float4*)(qn + l4);
        q1[h] = *(const float4*)(qn + 256 + l4);
        qp[h] = q_pe[((size_t)b * H + wave * 4 + h) * 64 + lane];
    }

    float m_run[4], l_run[4];
    float4 o0[4], o1[4];
#pragma unroll
    for (int h = 0; h < 4; ++h) {
        m_run[h] = -INFINITY; l_run[h] = 0.f;
        o0[h] = make_float4(0.f, 0.f, 0.f, 0.f);
        o1[h] = make_float4(0.f, 0.f, 0.f, 0.f);
    }

    stage(0, 0);
    asm volatile("s_waitcnt vmcnt(0)" ::: "memory");
    __syncthreads();
    if (ptile == 0) { patch(0, rel); __syncthreads(); }

    int cur = 0;
    for (int tile = 0; tile < NT; ++tile) {
        if (tile + 1 < NT) stage(cur ^ 1, tile + 1);

        for (int r = 0; r < TR; ++r) {
            const float4 k0 = *(const float4*)&lds_kv[cur][r][l4];
            const float4 k1 = *(const float4*)&lds_kv[cur][r][256 + l4];
            const float  kp = lds_pe[cur][r][lane];

            float sc[4];
#pragma unroll
            for (int h = 0; h < 4; ++h) {
                sc[h] = q0[h].x * k0.x + q0[h].y * k0.y + q0[h].z * k0.z + q0[h].w * k0.w
                      + q1[h].x * k1.x + q1[h].y * k1.y + q1[h].z * k1.z + q1[h].w * k1.w
                      + qp[h] * kp;
            }
#pragma unroll
            for (int msk = 32; msk >= 1; msk >>= 1) {
#pragma unroll
                for (int h = 0; h < 4; ++h) sc[h] += __shfl_xor(sc[h], msk);
            }
#pragma unroll
            for (int h = 0; h < 4; ++h) {
                const float s = sc[h] * SCALE_C;
                if (s > m_run[h] + 8.0f) { // wave-uniform branch
                    const float alpha = __expf(m_run[h] - s);
                    l_run[h] *= alpha;
                    o0[h].x *= alpha; o0[h].y *= alpha; o0[h].z *= alpha; o0[h].w *= alpha;
                    o1[h].x *= alpha; o1[h].y *= alpha; o1[h].z *= alpha; o1[h].w *= alpha;
                    m_run[h] = s;
                }
                const float p = __expf(s - m_run[h]); // bounded by e^8
                l_run[h] += p;
                o0[h].x += p * k0.x; o0[h].y += p * k0.y;
                o0[h].z += p * k0.z; o0[h].w += p * k0.w;
                o1[h].x += p * k1.x; o1[h].y += p * k1.y;
                o1[h].z += p * k1.z; o1[h].w += p * k1.w;
            }
        }

        asm volatile("s_waitcnt vmcnt(0)" ::: "memory");
        __syncthreads();
        if (tile + 1 < NT && ptile == tile + 1) {
            patch(cur ^ 1, rel - ptile * TR);
            __syncthreads();
        }
        cur ^= 1;
    }

    float* po = part_o + (((size_t)b * NC + c) * H) * LORA;
#pragma unroll
    for (int h = 0; h < 4; ++h) {
        float* p = po + (size_t)(wave * 4 + h) * LORA;
        *(float4*)(p + l4) = o0[h];
        *(float4*)(p + 256 + l4) = o1[h];
    }
    if (lane == 0) {
        float* pml = part_ml + (((size_t)b * NC + c) * H + wave * 4) * 2;
#pragma unroll
        for (int h = 0; h < 4; ++h) {
            pml[2 * h] = m_run[h];
            pml[2 * h + 1] = l_run[h];
        }
    }
}

// ---------------- Kernel 5: combine partials -> o (LDS), fused v = o . W_UV
__global__ __launch_bounds__(256) void k_combine(
    const float* __restrict__ part_o, const float* __restrict__ part_ml,
    const float* __restrict__ W_UV, float* __restrict__ v) {
    const int b0 = blockIdx.x * 4, h = blockIdx.y, t = threadIdx.x;
    __shared__ float ml_s[4][NC][2];
    __shared__ float o_s[4][LORA]; // 8 KB
    if (t < 256) {
        const int b2 = t >> 6, c = (t >> 1) & 31, w = t & 1;
        ml_s[b2][c][w] = part_ml[(((size_t)(b0 + b2) * NC + c) * H + h) * 2 + w];
    }
    __syncthreads();
    float m_b[4], inv_l[4];
#pragma unroll
    for (int b2 = 0; b2 < 4; ++b2) {
        float m = -INFINITY;
        for (int c = 0; c < NC; c++) m = fmaxf(m, ml_s[b2][c][0]);
        float l = 0.f;
        for (int c = 0; c < NC; c++) l += ml_s[b2][c][1] * __expf(ml_s[b2][c][0] - m);
        m_b[b2] = m;
        inv_l[b2] = 1.0f / l;
    }
    for (int i = t; i < 4 * LORA; i += 256) {
        const int b2 = i >> 9, li = i & 511;
        float acc = 0.f;
        for (int c = 0; c < NC; c++) {
            acc += part_o[(((size_t)(b0 + b2) * NC + c) * H + h) * LORA + li] *
                   __expf(ml_s[b2][c][0] - m_b[b2]);
        }
        o_s[b2][li] = acc * inv_l[b2];
    }
    __syncthreads();
    const int vi = t & 127, bp = t >> 7;
    float acc0 = 0.f, acc1 = 0.f;
    for (int l = 0; l < LORA; l += 4) {
        const float w0 = W_UV[(size_t)(l + 0) * (H * VH) + h * VH + vi];
        const float w1 = W_UV[(size_t)(l + 1) * (H * VH) + h * VH + vi];
        const float w2 = W_UV[(size_t)(l + 2) * (H * VH) + h * VH + vi];
        const float w3 = W_UV[(size_t)(l + 3) * (H * VH) + h * VH + vi];
        const float4 oa = *(const float4*)&o_s[bp * 2][l];
        const float4 ob = *(const float4*)&o_s[bp * 2 + 1][l];
        acc0 += oa.x * w0 + oa.y * w1 + oa.z * w2 + oa.w * w3;
        acc1 += ob.x * w0 + ob.y * w1 + ob.z * w2 + ob.w * w3;
    }
    v[(size_t)(b0 + bp * 2) * (H * VH) + h * VH + vi] = acc0;
    v[(size_t)(b0 + bp * 2 + 1) * (H * VH) + h * VH + vi] = acc1;
}

// ---------------- Kernel 6: out_part[ks] = V[:, k-slice] @ W_O[k-slice, :]
__global__ void k_out(const float* __restrict__ v, const float* __restrict__ W_O,
                      float* __restrict__ out_part) {
    const int dsl = blockIdx.x, ksl = blockIdx.y, t = threadIdx.x;
    const int d0 = dsl * 128, k0 = ksl * 128;
    __shared__ float vs[32][128];
    for (int i = t; i < 32 * 128; i += 256) {
        const int bi = i >> 7, kk = i & 127;
        vs[bi][kk] = v[(size_t)bi * DM + k0 + kk];
    }
    __syncthreads();
    const int dl = t & 127, bh = t >> 7;
    float acc[16];
#pragma unroll
    for (int i = 0; i < 16; i++) acc[i] = 0.f;
    for (int kk = 0; kk < 128; kk += 4) {
        const float w0 = W_O[(size_t)(k0 + kk + 0) * DM + d0 + dl];
        const float w1 = W_O[(size_t)(k0 + kk + 1) * DM + d0 + dl];
        const float w2 = W_O[(size_t)(k0 + kk + 2) * DM + d0 + dl];
        const float w3 = W_O[(size_t)(k0 + kk + 3) * DM + d0 + dl];
#pragma unroll
        for (int i = 0; i < 16; i++) {
            const float4 vv = *(const float4*)&vs[bh * 16 + i][kk];
            acc[i] += vv.x * w0 + vv.y * w1 + vv.z * w2 + vv.w * w3;
        }
    }
    float* op = out_part + (size_t)ksl * 32 * DM;
#pragma unroll
    for (int i = 0; i < 16; i++) op[(size_t)(bh * 16 + i) * DM + d0 + dl] = acc[i];
}

// ---------------- Kernel 7: reduce the 16 split-K partials
__global__ void k_out_reduce(const float* __restrict__ out_part, float* __restrict__ out) {
    const int idx = blockIdx.x * 256 + threadIdx.x;
    float4 acc = make_float4(0.f, 0.f, 0.f, 0.f);
    for (int ks = 0; ks < 16; ks++) {
        float4 p = *(const float4*)(out_part + (size_t)ks * (32 * DM) + (size_t)idx * 4);
        acc.x += p.x; acc.y += p.y; acc.z += p.z; acc.w += p.w;
    }
    *(float4*)(out + (size_t)idx * 4) = acc;
}

extern "C" void kernel_launch(void* const* d_in, const int* in_sizes, int n_in,
                              void* d_out, int out_size, void* d_ws, size_t ws_size,
                              hipStream_t stream) {
    const float* q_c        = (const float*)d_in[0];
    const float* k_c_normed = (const float*)d_in[1];
    const float* k_pe       = (const float*)d_in[2];
    const float* kv_c_cache = (const float*)d_in[3];
    const float* k_pe_cache = (const float*)d_in[4];
    const float* W_UQ       = (const float*)d_in[5];
    const float* W_UK       = (const float*)d_in[6];
    const float* W_QR       = (const float*)d_in[7];
    const float* W_UV       = (const float*)d_in[8];
    const float* W_O        = (const float*)d_in[9];
    const int*   pos        = (const int*)d_in[10];

    float* ws = (float*)d_ws;
    float* q_t      = ws;                       // 65536
    float* qr       = q_t + 65536;              // 32768
    float* q_pe     = qr + 32768;               // 32768
    float* kpe_rot  = q_pe + 32768;             // 2048
    float* q_nope   = kpe_rot + 2048;           // 262144
    float* part_o   = q_nope + 262144;          // 8388608
    float* part_ml  = part_o + (size_t)B * NC * H * LORA;   // 32768
    float* v        = part_ml + (size_t)B * NC * H * 2;     // 65536
    float* out_part = v + 65536;                // 1048576
    float* proj_part = out_part + (size_t)16 * 32 * DM;     // 2359296

    k_proj_part<<<dim3(NKS, 12), 256, 0, stream>>>(q_c, W_UQ, W_QR, proj_part);
    k_proj_reduce<<<96, 256, 0, stream>>>(proj_part, q_t, qr);
    k_rope<<<32, 256, 0, stream>>>(qr, k_pe, pos, q_pe, kpe_rot);
    k_qnope<<<dim3(8, 8, 16), 256, 0, stream>>>(q_t, W_UK, q_nope);
    k_flash<<<B * NC, 256, 0, stream>>>(q_nope, q_pe, kv_c_cache, k_pe_cache,
                                        k_c_normed, kpe_rot, pos, part_o, part_ml);
    k_combine<<<dim3(8, 16), 256, 0, stream>>>(part_o, part_ml, W_UV, v);
    k_out<<<dim3(16, 16), 256, 0, stream>>>(v, W_O, out_part);
    k_out_reduce<<<64, 256, 0, stream>>>(out_part, (float*)d_out);
}

// Round 7
// 214.840 us; speedup vs baseline: 1.2790x; 1.2790x over previous
//
#include <hip/hip_runtime.h>
#include <hip/hip_bf16.h>
#include <math.h>

#define B 32
#define S 4096
#define H 16
#define QC 1536
#define LORA 512
#define ROPE 64
#define NOPE 128
#define VH 128
#define DM 2048
#define NC 32          // chunks per batch for flash split-K
#define CHUNK (S / NC) // 128 rows per chunk
#define TR 8           // rows per staged LDS tile
#define NT (CHUNK / TR)
#define NKS 24         // k-slices for proj1 split-K (1536/64)

__device__ __constant__ float SCALE_C = 0.07216878364870323f; // 1/sqrt(192)

// ---------------- Kernel 1a: proj partials. grid (NKS=24, 12 col-slices), 256 thr.
__global__ __launch_bounds__(256) void k_proj_part(
    const float* __restrict__ q_c, const float* __restrict__ W_UQ,
    const float* __restrict__ W_QR, float* __restrict__ part) {
    const int ks = blockIdx.x, cs = blockIdx.y, t = threadIdx.x;
    const int k0 = ks * 64;
    __shared__ float qs[64][32]; // [k][b]
    for (int i = t; i < 64 * 32; i += 256) {
        const int k = i >> 5, b2 = i & 31;
        qs[k][b2] = q_c[(size_t)b2 * QC + k0 + k];
    }
    __syncthreads();
    const int tc = t & 63, tb = t >> 6;
    const int col = cs * 256 + tc * 4;
    const float* W; int N, coll;
    if (cs < 8) { W = W_UQ; N = 2048; coll = col; }
    else        { W = W_QR; N = 1024; coll = col - 2048; }
    float4 acc[8];
#pragma unroll
    for (int i = 0; i < 8; i++) acc[i] = make_float4(0.f, 0.f, 0.f, 0.f);
#pragma unroll 4
    for (int k = 0; k < 64; ++k) {
        const float4 w4 = *(const float4*)(W + (size_t)(k0 + k) * N + coll);
        const float4 a1 = *(const float4*)&qs[k][tb * 8];
        const float4 a2 = *(const float4*)&qs[k][tb * 8 + 4];
        acc[0].x += a1.x * w4.x; acc[0].y += a1.x * w4.y; acc[0].z += a1.x * w4.z; acc[0].w += a1.x * w4.w;
        acc[1].x += a1.y * w4.x; acc[1].y += a1.y * w4.y; acc[1].z += a1.y * w4.z; acc[1].w += a1.y * w4.w;
        acc[2].x += a1.z * w4.x; acc[2].y += a1.z * w4.y; acc[2].z += a1.z * w4.z; acc[2].w += a1.z * w4.w;
        acc[3].x += a1.w * w4.x; acc[3].y += a1.w * w4.y; acc[3].z += a1.w * w4.z; acc[3].w += a1.w * w4.w;
        acc[4].x += a2.x * w4.x; acc[4].y += a2.x * w4.y; acc[4].z += a2.x * w4.z; acc[4].w += a2.x * w4.w;
        acc[5].x += a2.y * w4.x; acc[5].y += a2.y * w4.y; acc[5].z += a2.y * w4.z; acc[5].w += a2.y * w4.w;
        acc[6].x += a2.z * w4.x; acc[6].y += a2.z * w4.y; acc[6].z += a2.z * w4.z; acc[6].w += a2.z * w4.w;
        acc[7].x += a2.w * w4.x; acc[7].y += a2.w * w4.y; acc[7].z += a2.w * w4.z; acc[7].w += a2.w * w4.w;
    }
#pragma unroll
    for (int j = 0; j < 8; j++) {
        const int b2 = tb * 8 + j;
        *(float4*)(part + ((size_t)ks * 32 + b2) * 3072 + col) = acc[j];
    }
}

// ---------------- Kernel 1b: reduce 24 partials -> q_t (32x2048), qr (32x1024)
__global__ void k_proj_reduce(const float* __restrict__ part, float* __restrict__ q_t,
                              float* __restrict__ qr) {
    const int idx = blockIdx.x * 256 + threadIdx.x;
    const int b = idx / 768, c4 = idx % 768;
    const int col = c4 * 4;
    float4 acc = make_float4(0.f, 0.f, 0.f, 0.f);
    for (int ks = 0; ks < NKS; ks++) {
        const float4 p = *(const float4*)(part + ((size_t)ks * 32 + b) * 3072 + col);
        acc.x += p.x; acc.y += p.y; acc.z += p.z; acc.w += p.w;
    }
    if (col < 2048) *(float4*)(q_t + (size_t)b * 2048 + col) = acc;
    else            *(float4*)(qr + (size_t)b * 1024 + col - 2048) = acc;
}

// ---------------- Kernel 2: RoPE  (q_pe from qr; kpe_rot from k_pe)
__global__ void k_rope(const float* __restrict__ qr, const float* __restrict__ k_pe,
                       const int* __restrict__ pos_arr, float* __restrict__ q_pe,
                       float* __restrict__ kpe_rot) {
    const int b = blockIdx.x, t = threadIdx.x;
    const int pos = pos_arr[b];
    for (int p = t; p < (H + 1) * 32; p += 256) {
        const int j = p & 31;
        const int grp = p >> 5;
        const double inv = pow(10000.0, -(double)j / 32.0);
        const double f = (double)pos * inv;
        const float c = (float)cos(f), s = (float)sin(f);
        if (grp < H) {
            const float* x = qr + (size_t)b * 1024 + grp * 64;
            float* o = q_pe + (size_t)b * 1024 + grp * 64;
            const float x1 = x[j], x2 = x[j + 32];
            o[j] = x1 * c - x2 * s;
            o[j + 32] = x2 * c + x1 * s;
        } else {
            const float* x = k_pe + (size_t)b * 64;
            float* o = kpe_rot + (size_t)b * 64;
            const float x1 = x[j], x2 = x[j + 32];
            o[j] = x1 * c - x2 * s;
            o[j + 32] = x2 * c + x1 * s;
        }
    }
}

// ---------------- Kernel 3: q_nope[b,h,l] = sum_n q_t[b,h,n] * W_UK[l,h,n]
__global__ __launch_bounds__(256) void k_qnope(
    const float* __restrict__ q_t, const float* __restrict__ W_UK,
    float* __restrict__ q_nope) {
    const int l0 = blockIdx.x * 64, b0 = blockIdx.y * 4, h = blockIdx.z;
    const int t = threadIdx.x;
    __shared__ float qs[4][NOPE];
    for (int i = t; i < 4 * NOPE; i += 256) {
        const int b2 = i >> 7, n = i & 127;
        qs[b2][n] = q_t[(size_t)(b0 + b2) * 2048 + h * NOPE + n];
    }
    __syncthreads();
    const int wave = t >> 6, lane = t & 63;
    const int half = lane >> 5, nl = (lane & 31) * 4;
    for (int sw = 0; sw < 8; ++sw) {
        const int l = l0 + sw * 8 + wave * 2 + half;
        const float4 w4 = *(const float4*)(W_UK + ((size_t)l * H + h) * NOPE + nl);
#pragma unroll
        for (int b2 = 0; b2 < 4; ++b2) {
            const float4 a4 = *(const float4*)&qs[b2][nl];
            float d = a4.x * w4.x + a4.y * w4.y + a4.z * w4.z + a4.w * w4.w;
            d += __shfl_xor(d, 16);
            d += __shfl_xor(d, 8);
            d += __shfl_xor(d, 4);
            d += __shfl_xor(d, 2);
            d += __shfl_xor(d, 1);
            if ((lane & 31) == 0)
                q_nope[((size_t)(b0 + b2) * H + h) * LORA + l] = d;
        }
    }
}

// ---------------- Kernel 4: flash decode, LDS double-buffered via global_load_lds
// Block = 128 threads = 2 waves = 8 groups of 16 lanes; group g owns heads 2g, 2g+1.
// Thread (g,j) holds q elems {4j..4j+3}+64k (k=0..8; k=8 = RoPE) for BOTH heads.
// Per row: kv loaded once into regs, serves QK+PV for 2 heads -> half the LDS
// instruction traffic per block vs 1-head-per-group. Reduce: 4-level DPP
// (masks 8/4/2/1, within-16 only). Defer-max online softmax (THR=8).
__global__ __launch_bounds__(128) void k_flash(
    const float* __restrict__ q_nope, const float* __restrict__ q_pe,
    const float* __restrict__ kv_cache, const float* __restrict__ kpe_cache,
    const float* __restrict__ k_c_normed, const float* __restrict__ kpe_rot,
    const int* __restrict__ pos_arr, float* __restrict__ part_o,
    float* __restrict__ part_ml) {
    __shared__ float lds_kv[2][TR][LORA]; // 32 KB
    __shared__ float lds_pe[2][TR][ROPE]; //  4 KB
    const int blk = blockIdx.x;
    const int b = blk / NC, c = blk % NC;
    const int t = threadIdx.x;
    const int g = t >> 4, j = t & 15;     // 8 groups of 16
    const int wave = t >> 6, lane = t & 63;
    const int pos = pos_arr[b];
    const int s0 = c * CHUNK;
    const int rel = pos - s0;
    const int ptile = (rel >= 0 && rel < CHUNK) ? (rel / TR) : -1;

    const char* kvg = (const char*)kv_cache + (size_t)b * S * LORA * 4;
    const char* peg = (const char*)kpe_cache + (size_t)b * S * ROPE * 4;
    const float* kc_b = k_c_normed + (size_t)b * LORA;
    const float* kr_b = kpe_rot + (size_t)b * ROPE;

    const int wo = wave * 1024 + lane * 16;

    auto stage = [&](int bi, int tile) {
        const char* gk = kvg + (size_t)(s0 + tile * TR) * (LORA * 4);
        char* lk = (char*)&lds_kv[bi][0][0];
#pragma unroll
        for (int i = 0; i < 8; ++i) {
            __builtin_amdgcn_global_load_lds(
                (const __attribute__((address_space(1))) void*)(gk + i * 2048 + wo),
                (__attribute__((address_space(3))) void*)(lk + i * 2048 + wave * 1024),
                16, 0, 0);
        }
        const char* gp = peg + (size_t)(s0 + tile * TR) * (ROPE * 4);
        char* lp = (char*)&lds_pe[bi][0][0];
        __builtin_amdgcn_global_load_lds(
            (const __attribute__((address_space(1))) void*)(gp + wo),
            (__attribute__((address_space(3))) void*)(lp + wave * 1024),
            16, 0, 0);
    };
    auto patch = [&](int bi, int prow) {
        ((float4*)&lds_kv[bi][prow][0])[t] = ((const float4*)kc_b)[t];
        if (t < 16)
            ((float4*)&lds_pe[bi][prow][0])[t] = ((const float4*)kr_b)[t];
    };

    // q fragments for this group's 2 heads, this lane's dim chunk
    float4 q4[2][9];
#pragma unroll
    for (int h = 0; h < 2; ++h) {
        const float* qn = q_nope + ((size_t)b * H + 2 * g + h) * LORA;
#pragma unroll
        for (int k = 0; k < 8; k++) q4[h][k] = *(const float4*)(qn + 4 * j + 64 * k);
        q4[h][8] = *(const float4*)(q_pe + ((size_t)b * H + 2 * g + h) * 64 + 4 * j);
    }

    float m_run[2] = {-INFINITY, -INFINITY}, l_run[2] = {0.f, 0.f};
    float4 o_acc[2][8];
#pragma unroll
    for (int h = 0; h < 2; ++h)
#pragma unroll
        for (int k = 0; k < 8; k++) o_acc[h][k] = make_float4(0.f, 0.f, 0.f, 0.f);

    stage(0, 0);
    asm volatile("s_waitcnt vmcnt(0)" ::: "memory");
    __syncthreads();
    if (ptile == 0) { patch(0, rel); __syncthreads(); }

    int cur = 0;
    for (int tile = 0; tile < NT; ++tile) {
        if (tile + 1 < NT) stage(cur ^ 1, tile + 1);

        for (int r = 0; r < TR; ++r) {
            const float* kvr = &lds_kv[cur][r][0];
            float4 kv4[8];
#pragma unroll
            for (int k = 0; k < 8; k++) kv4[k] = *(const float4*)(kvr + 4 * j + 64 * k);
            float4 p4 = *(const float4*)(&lds_pe[cur][r][0] + 4 * j);

            float sc[2];
#pragma unroll
            for (int h = 0; h < 2; ++h) {
                float acc = 0.f;
#pragma unroll
                for (int k = 0; k < 8; k++)
                    acc += q4[h][k].x * kv4[k].x + q4[h][k].y * kv4[k].y +
                           q4[h][k].z * kv4[k].z + q4[h][k].w * kv4[k].w;
                acc += q4[h][8].x * p4.x + q4[h][8].y * p4.y +
                       q4[h][8].z * p4.z + q4[h][8].w * p4.w;
                sc[h] = acc;
            }
            // 4-level within-16 DPP reduce for both heads
#pragma unroll
            for (int msk = 8; msk >= 1; msk >>= 1) {
                sc[0] += __shfl_xor(sc[0], msk);
                sc[1] += __shfl_xor(sc[1], msk);
            }
#pragma unroll
            for (int h = 0; h < 2; ++h) {
                const float s = sc[h] * SCALE_C;
                if (s > m_run[h] + 8.0f) { // defer-max rescale
                    const float alpha = __expf(m_run[h] - s); // exp(-inf)=0 first hit
                    l_run[h] *= alpha;
#pragma unroll
                    for (int k = 0; k < 8; k++) {
                        o_acc[h][k].x *= alpha; o_acc[h][k].y *= alpha;
                        o_acc[h][k].z *= alpha; o_acc[h][k].w *= alpha;
                    }
                    m_run[h] = s;
                }
                const float p = __expf(s - m_run[h]); // bounded by e^8
                l_run[h] += p;
#pragma unroll
                for (int k = 0; k < 8; k++) {
                    o_acc[h][k].x += p * kv4[k].x; o_acc[h][k].y += p * kv4[k].y;
                    o_acc[h][k].z += p * kv4[k].z; o_acc[h][k].w += p * kv4[k].w;
                }
            }
        }

        asm volatile("s_waitcnt vmcnt(0)" ::: "memory");
        __syncthreads();
        if (tile + 1 < NT && ptile == tile + 1) {
            patch(cur ^ 1, rel - ptile * TR);
            __syncthreads();
        }
        cur ^= 1;
    }

    float* po = part_o + (((size_t)b * NC + c) * H) * LORA;
#pragma unroll
    for (int h = 0; h < 2; ++h) {
        float* p = po + (size_t)(2 * g + h) * LORA;
#pragma unroll
        for (int k = 0; k < 8; k++) *(float4*)(p + 4 * j + 64 * k) = o_acc[h][k];
    }
    if (j == 0) {
        float* pml = part_ml + (((size_t)b * NC + c) * H + 2 * g) * 2;
        pml[0] = m_run[0]; pml[1] = l_run[0];
        pml[2] = m_run[1]; pml[3] = l_run[1];
    }
}

// ---------------- Kernel 5: combine partials -> o (LDS), fused v = o . W_UV
__global__ __launch_bounds__(256) void k_combine(
    const float* __restrict__ part_o, const float* __restrict__ part_ml,
    const float* __restrict__ W_UV, float* __restrict__ v) {
    const int b0 = blockIdx.x * 4, h = blockIdx.y, t = threadIdx.x;
    __shared__ float ml_s[4][NC][2];
    __shared__ float o_s[4][LORA]; // 8 KB
    if (t < 256) {
        const int b2 = t >> 6, c = (t >> 1) & 31, w = t & 1;
        ml_s[b2][c][w] = part_ml[(((size_t)(b0 + b2) * NC + c) * H + h) * 2 + w];
    }
    __syncthreads();
    float m_b[4], inv_l[4];
#pragma unroll
    for (int b2 = 0; b2 < 4; ++b2) {
        float m = -INFINITY;
        for (int c = 0; c < NC; c++) m = fmaxf(m, ml_s[b2][c][0]);
        float l = 0.f;
        for (int c = 0; c < NC; c++) l += ml_s[b2][c][1] * __expf(ml_s[b2][c][0] - m);
        m_b[b2] = m;
        inv_l[b2] = 1.0f / l;
    }
    for (int i = t; i < 4 * LORA; i += 256) {
        const int b2 = i >> 9, li = i & 511;
        float acc = 0.f;
        for (int c = 0; c < NC; c++) {
            acc += part_o[(((size_t)(b0 + b2) * NC + c) * H + h) * LORA + li] *
                   __expf(ml_s[b2][c][0] - m_b[b2]);
        }
        o_s[b2][li] = acc * inv_l[b2];
    }
    __syncthreads();
    const int vi = t & 127, bp = t >> 7;
    float acc0 = 0.f, acc1 = 0.f;
    for (int l = 0; l < LORA; l += 4) {
        const float w0 = W_UV[(size_t)(l + 0) * (H * VH) + h * VH + vi];
        const float w1 = W_UV[(size_t)(l + 1) * (H * VH) + h * VH + vi];
        const float w2 = W_UV[(size_t)(l + 2) * (H * VH) + h * VH + vi];
        const float w3 = W_UV[(size_t)(l + 3) * (H * VH) + h * VH + vi];
        const float4 oa = *(const float4*)&o_s[bp * 2][l];
        const float4 ob = *(const float4*)&o_s[bp * 2 + 1][l];
        acc0 += oa.x * w0 + oa.y * w1 + oa.z * w2 + oa.w * w3;
        acc1 += ob.x * w0 + ob.y * w1 + ob.z * w2 + ob.w * w3;
    }
    v[(size_t)(b0 + bp * 2) * (H * VH) + h * VH + vi] = acc0;
    v[(size_t)(b0 + bp * 2 + 1) * (H * VH) + h * VH + vi] = acc1;
}

// ---------------- Kernel 6: out_part[ks] = V[:, k-slice] @ W_O[k-slice, :]
__global__ void k_out(const float* __restrict__ v, const float* __restrict__ W_O,
                      float* __restrict__ out_part) {
    const int dsl = blockIdx.x, ksl = blockIdx.y, t = threadIdx.x;
    const int d0 = dsl * 128, k0 = ksl * 128;
    __shared__ float vs[32][128];
    for (int i = t; i < 32 * 128; i += 256) {
        const int bi = i >> 7, kk = i & 127;
        vs[bi][kk] = v[(size_t)bi * DM + k0 + kk];
    }
    __syncthreads();
    const int dl = t & 127, bh = t >> 7;
    float acc[16];
#pragma unroll
    for (int i = 0; i < 16; i++) acc[i] = 0.f;
    for (int kk = 0; kk < 128; kk += 4) {
        const float w0 = W_O[(size_t)(k0 + kk + 0) * DM + d0 + dl];
        const float w1 = W_O[(size_t)(k0 + kk + 1) * DM + d0 + dl];
        const float w2 = W_O[(size_t)(k0 + kk + 2) * DM + d0 + dl];
        const float w3 = W_O[(size_t)(k0 + kk + 3) * DM + d0 + dl];
#pragma unroll
        for (int i = 0; i < 16; i++) {
            const float4 vv = *(const float4*)&vs[bh * 16 + i][kk];
            acc[i] += vv.x * w0 + vv.y * w1 + vv.z * w2 + vv.w * w3;
        }
    }
    float* op = out_part + (size_t)ksl * 32 * DM;
#pragma unroll
    for (int i = 0; i < 16; i++) op[(size_t)(bh * 16 + i) * DM + d0 + dl] = acc[i];
}

// ---------------- Kernel 7: reduce the 16 split-K partials
__global__ void k_out_reduce(const float* __restrict__ out_part, float* __restrict__ out) {
    const int idx = blockIdx.x * 256 + threadIdx.x;
    float4 acc = make_float4(0.f, 0.f, 0.f, 0.f);
    for (int ks = 0; ks < 16; ks++) {
        float4 p = *(const float4*)(out_part + (size_t)ks * (32 * DM) + (size_t)idx * 4);
        acc.x += p.x; acc.y += p.y; acc.z += p.z; acc.w += p.w;
    }
    *(float4*)(out + (size_t)idx * 4) = acc;
}

extern "C" void kernel_launch(void* const* d_in, const int* in_sizes, int n_in,
                              void* d_out, int out_size, void* d_ws, size_t ws_size,
                              hipStream_t stream) {
    const float* q_c        = (const float*)d_in[0];
    const float* k_c_normed = (const float*)d_in[1];
    const float* k_pe       = (const float*)d_in[2];
    const float* kv_c_cache = (const float*)d_in[3];
    const float* k_pe_cache = (const float*)d_in[4];
    const float* W_UQ       = (const float*)d_in[5];
    const float* W_UK       = (const float*)d_in[6];
    const float* W_QR       = (const float*)d_in[7];
    const float* W_UV       = (const float*)d_in[8];
    const float* W_O        = (const float*)d_in[9];
    const int*   pos        = (const int*)d_in[10];

    float* ws = (float*)d_ws;
    float* q_t      = ws;                       // 65536
    float* qr       = q_t + 65536;              // 32768
    float* q_pe     = qr + 32768;               // 32768
    float* kpe_rot  = q_pe + 32768;             // 2048
    float* q_nope   = kpe_rot + 2048;           // 262144
    float* part_o   = q_nope + 262144;          // 8388608
    float* part_ml  = part_o + (size_t)B * NC * H * LORA;   // 32768
    float* v        = part_ml + (size_t)B * NC * H * 2;     // 65536
    float* out_part = v + 65536;                // 1048576
    float* proj_part = out_part + (size_t)16 * 32 * DM;     // 2359296

    k_proj_part<<<dim3(NKS, 12), 256, 0, stream>>>(q_c, W_UQ, W_QR, proj_part);
    k_proj_reduce<<<96, 256, 0, stream>>>(proj_part, q_t, qr);
    k_rope<<<32, 256, 0, stream>>>(qr, k_pe, pos, q_pe, kpe_rot);
    k_qnope<<<dim3(8, 8, 16), 256, 0, stream>>>(q_t, W_UK, q_nope);
    k_flash<<<B * NC, 128, 0, stream>>>(q_nope, q_pe, kv_c_cache, k_pe_cache,
                                        k_c_normed, kpe_rot, pos, part_o, part_ml);
    k_combine<<<dim3(8, 16), 256, 0, stream>>>(part_o, part_ml, W_UV, v);
    k_out<<<dim3(16, 16), 256, 0, stream>>>(v, W_O, out_part);
    k_out_reduce<<<64, 256, 0, stream>>>(out_part, (float*)d_out);
}